// Round 16
// baseline (350.224 us; speedup 1.0000x reference)
//
#include <hip/hip_runtime.h>

// ---------------------------------------------------------------------------
// Transformer block for MI355X (gfx950).
// R24: attn KVBLK 64->128 (two 64-wide halves per barrier).  R23 counters:
// BM=256 took fc1/qkv off the top-5; attn now leads at 56.0us with
// MfmaUtil 21 / VALU 44.6 / Occ 18.9 / 4.3M bank-conflict -- ~4070 cyc per
// block-iter vs ~1000 issue = per-iter barrier overhead paid 33x/block.
// The per-CU-iteration lever (fc2 BK=64: 56.8->27; fc1/qkv BM=256) applied
// to attn: stage 128 k-rows per barrier as TWO 64-wide halves so all LDS
// layouts/swizzles/fragment reads stay byte-identical; compute runs the
// existing 64-wide body twice (hh=0,1).  Block iters 33 -> 17 uniform
// ((j>>1)+1 + ((31-j)>>1)+1 = 17).  Fully-masked half (kt2>qt, even qt's
// last tile) skipped wave-uniformly.  Diag mask delta unchanged.  LDS 64KB
// x 2 blocks/CU = 128 <= 160KB.  GEMMs keep R23 config (qkv/fc1 BM=256
// BK=32; proj BN=64; fc2 BK=64+SWZ).
// ---------------------------------------------------------------------------

typedef short  bf16x8 __attribute__((ext_vector_type(8)));
typedef short  bf16x4 __attribute__((ext_vector_type(4)));
typedef float  fx4    __attribute__((ext_vector_type(4)));
typedef int    ix2    __attribute__((ext_vector_type(2)));

#define DEV static __device__ __forceinline__

DEV short f2bf(float f) {                 // round-to-nearest-even fp32 -> bf16
    unsigned u = __builtin_bit_cast(unsigned, f);
    u += 0x7fffu + ((u >> 16) & 1u);
    return (short)(u >> 16);
}

// address-space casts for global_load_lds
#define AS1(p) ((__attribute__((address_space(1))) void*)(p))
#define AS3(p) ((__attribute__((address_space(3))) void*)(p))

// ---------------------------------------------------------------------------
// LayerNorm: fp32 [4096][1024] -> bf16 [4096][1024].  One block (256t) / row.
// ---------------------------------------------------------------------------
__global__ __launch_bounds__(256) void ln_kernel(const float* __restrict__ x,
                                                 const float* __restrict__ w,
                                                 const float* __restrict__ b,
                                                 short* __restrict__ out)
{
    int row = blockIdx.x;
    int tid = threadIdx.x;
    const float4 v = *(const float4*)(x + (size_t)row * 1024 + tid * 4);
    float s = v.x + v.y + v.z + v.w;
    float q = v.x * v.x + v.y * v.y + v.z * v.z + v.w * v.w;
#pragma unroll
    for (int off = 32; off > 0; off >>= 1) {
        s += __shfl_down(s, off);
        q += __shfl_down(q, off);
    }
    __shared__ float ls[4], lq[4];
    if ((tid & 63) == 0) { ls[tid >> 6] = s; lq[tid >> 6] = q; }
    __syncthreads();
    float S  = ls[0] + ls[1] + ls[2] + ls[3];
    float Q  = lq[0] + lq[1] + lq[2] + lq[3];
    float mu  = S * (1.0f / 1024.0f);
    float var = Q * (1.0f / 1024.0f) - mu * mu;
    float inv = rsqrtf(var + 1e-5f);
    float4 wv = *(const float4*)(w + tid * 4);
    float4 bv = *(const float4*)(b + tid * 4);
    bf16x4 o;
    o[0] = f2bf((v.x - mu) * inv * wv.x + bv.x);
    o[1] = f2bf((v.y - mu) * inv * wv.y + bv.y);
    o[2] = f2bf((v.z - mu) * inv * wv.z + bv.z);
    o[3] = f2bf((v.w - mu) * inv * wv.w + bv.w);
    *(bf16x4*)(out + (size_t)row * 1024 + tid * 4) = o;
}

// ---------------------------------------------------------------------------
// Weight transpose+cast: fp32 [R][C] -> bf16 [C][R].  64x64 tiles, 256 thr.
// ---------------------------------------------------------------------------
__global__ __launch_bounds__(256) void transpose_f32_bf16(const float* __restrict__ in,
                                                          short* __restrict__ out,
                                                          int R, int C)
{
    __shared__ float tile[64][65];
    int c0 = blockIdx.x * 64, r0 = blockIdx.y * 64;
    int t  = threadIdx.x;
    int tx = t & 15, ty = t >> 4;            // load: 16 col-segs x 16 rows
#pragma unroll
    for (int i = 0; i < 4; ++i) {
        int row = i * 16 + ty;
        float4 v = *(const float4*)(in + (size_t)(r0 + row) * C + c0 + tx * 4);
        tile[row][tx * 4 + 0] = v.x;
        tile[row][tx * 4 + 1] = v.y;
        tile[row][tx * 4 + 2] = v.z;
        tile[row][tx * 4 + 3] = v.w;
    }
    __syncthreads();
    int seg = t & 7;                         // out-row segment (8 in-rows)
#pragma unroll
    for (int p = 0; p < 2; ++p) {
        int orow = p * 32 + (t >> 3);        // out row = in col
        bf16x8 o;
#pragma unroll
        for (int u = 0; u < 8; ++u)
            o[u] = f2bf(tile[seg * 8 + u][orow]);
        *(bf16x8*)(out + (size_t)(c0 + orow) * R + r0 + seg * 8) = o;
    }
}

// ---------------------------------------------------------------------------
// Extract V^T per (b,h): qkv bf16 [4096][3072] cols[2048+h*64 .. +64)
//   -> vt [b][h][64][2048] (d-major, t contiguous) for PV's B-operand.
// ---------------------------------------------------------------------------
__global__ void vt_extract(const short* __restrict__ qkv, short* __restrict__ vt)
{
    __shared__ short tile[32][33];
    int t0 = blockIdx.x * 32, d0 = blockIdx.y * 32;
    int bh = blockIdx.z;                       // b*16 + h
    int tx = threadIdx.x, ty = threadIdx.y;
    size_t inbase  = (size_t)(bh >> 4) * 2048 * 3072 + 2048 + (bh & 15) * 64;
    size_t outbase = (size_t)bh * 64 * 2048;
#pragma unroll
    for (int dy = 0; dy < 32; dy += 8)
        tile[ty + dy][tx] = qkv[inbase + (size_t)(t0 + ty + dy) * 3072 + d0 + tx];
    __syncthreads();
#pragma unroll
    for (int dy = 0; dy < 32; dy += 8)
        vt[outbase + (size_t)(d0 + ty + dy) * 2048 + t0 + tx] = tile[tx][ty + dy];
}

// ---------------------------------------------------------------------------
// GEMM  C[M][N] = epi( A[M][K](bf16) * Bt[N][K](bf16)^T )
// BMxBN tile, NW=BM/32 waves (2*BM threads); each wave owns a 64x(BN/2)
// sub-tile: wr=(wv>>1)*64, wc=(wv&1)*(BN/2).  BK in {32,64},
// global_load_lds(16B), double-buffered LDS.  PIPE=1: counted-vmcnt
// 2-barrier loop; PIPE=0: classic full-drain loop.
// Swizzle: GR=BK/8 granules/row; LDS[row][g] = global[g ^ ((row>>1)&(GR-1))];
// k-half h read at granule (h*4+quad)^fr -> 2-way max bank spread.
// SWZ=1: XCD-aware block swizzle (bijective when gridDim.x*gridDim.y%8==0).
// ---------------------------------------------------------------------------
template <int BM, int BN, int BK, int SWZ, int PIPE, bool BIAS, bool GELU, bool RESID, bool OUT_BF16, bool PARTIAL>
__global__ __launch_bounds__(2 * BM) void gemm_bt(const short* __restrict__ A,
                                                  const short* __restrict__ Bt,
                                                  void* __restrict__ Cout,
                                                  void* __restrict__ Cout2,
                                                  const float* __restrict__ bias,
                                                  const float* __restrict__ resid,
                                                  int M, int N, int K)
{
    constexpr int NJ  = BN / 32;                   // 16-col tiles per wave
    constexpr int NW  = BM / 32;                   // waves per block
    constexpr int GR  = BK / 8;                    // granule slots per row
    constexpr int RPC = 512 / BK;                  // rows per 1KB chunk
    constexpr int NA  = (BM * BK) / 512;           // A chunks per buffer
    constexpr int NB  = (BN * BK) / 512;           // B chunks per buffer
    constexpr int LPS = (NA + NB) / NW;            // gload_lds per wave/stage
    __shared__ short As[2][BM * BK];
    __shared__ short Bs[2][BN * BK];
    int tid  = threadIdx.x;
    int lane = tid & 63, wv = tid >> 6;
    int quad = lane >> 4, l15 = lane & 15;
    int bx = blockIdx.x, by = blockIdx.y;
    if constexpr (SWZ) {
        int nx   = gridDim.x;
        int nper = nx * gridDim.y;                 // blocks per z-slice
        int flat = bx + nx * by;
        int cpx  = nper >> 3;                      // chunk per XCD
        int swz  = (flat & 7) * cpx + (flat >> 3); // bijective: nper % 8 == 0
        bx = swz % nx;
        by = swz / nx;
    }
    int m0 = by * BM, n0 = bx * BN;
    int SK   = gridDim.z;
    int kbeg = blockIdx.z * (K / SK);
    int NK   = (K / SK) / BK;
    int wr = (wv >> 1) * 64, wc = (wv & 1) * (BN / 2);
    fx4 acc[4][NJ] = {};
    int srow = lane / GR;                          // row within chunk
    int gl   = lane % GR;                          // granule slot
    int fr   = (l15 >> 1) & (GR - 1);              // fragment-read row XOR
    const short* Ab = A  + (size_t)m0 * K;
    const short* Bb = Bt + (size_t)n0 * K;

    auto stage = [&](int buf, int k0) {
#pragma unroll
        for (int c = wv; c < NA; c += NW) {
            int row  = c * RPC + srow;
            int scol = (gl ^ ((row >> 1) & (GR - 1))) * 8;
            __builtin_amdgcn_global_load_lds(AS1(Ab + (size_t)row * K + k0 + scol),
                                             AS3(&As[buf][c * 512]), 16, 0, 0);
        }
#pragma unroll
        for (int c = wv; c < NB; c += NW) {
            int row  = c * RPC + srow;
            int scol = (gl ^ ((row >> 1) & (GR - 1))) * 8;
            __builtin_amdgcn_global_load_lds(AS1(Bb + (size_t)row * K + k0 + scol),
                                             AS3(&Bs[buf][c * 512]), 16, 0, 0);
        }
    };

    auto compute_tile = [&](int cur) {
#pragma unroll
        for (int h = 0; h < BK / 32; ++h) {
            int rg = ((h * 4 + quad) ^ fr) * 8;
            bf16x8 af[4], bfr[NJ];
#pragma unroll
            for (int i = 0; i < 4; ++i)
                af[i] = *(const bf16x8*)&As[cur][(wr + i * 16 + l15) * BK + rg];
#pragma unroll
            for (int j = 0; j < NJ; ++j)
                bfr[j] = *(const bf16x8*)&Bs[cur][(wc + j * 16 + l15) * BK + rg];
#pragma unroll
            for (int i = 0; i < 4; ++i)
#pragma unroll
                for (int j = 0; j < NJ; ++j)
                    acc[i][j] = __builtin_amdgcn_mfma_f32_16x16x32_bf16(af[i], bfr[j], acc[i][j], 0, 0, 0);
        }
    };

    stage(0, kbeg);
    if constexpr (PIPE) {
        // Counted-vmcnt 2-barrier loop: prev tile's loads drained per-wave,
        // this tile's loads stay in flight across both barriers.
        for (int kt = 0; kt < NK; ++kt) {
            int cur = kt & 1;
            if (kt + 1 < NK) {
                stage(cur ^ 1, kbeg + (kt + 1) * BK);
                if constexpr      (LPS == 3) asm volatile("s_waitcnt vmcnt(3)" ::: "memory");
                else if constexpr (LPS == 4) asm volatile("s_waitcnt vmcnt(4)" ::: "memory");
                else if constexpr (LPS == 8) asm volatile("s_waitcnt vmcnt(8)" ::: "memory");
                else                         asm volatile("s_waitcnt vmcnt(0)" ::: "memory");
            } else {
                asm volatile("s_waitcnt vmcnt(0)" ::: "memory");
            }
            asm volatile("s_barrier" ::: "memory");   // B1: all waves' tile-kt loads done
            compute_tile(cur);
            asm volatile("s_barrier" ::: "memory");   // B2: all waves done reading buf[cur]
        }
    } else {
        __syncthreads();
        for (int kt = 0; kt < NK; ++kt) {
            int cur = kt & 1;
            if (kt + 1 < NK) stage(cur ^ 1, kbeg + (kt + 1) * BK);
            compute_tile(cur);
            __syncthreads();
        }
    }

    if constexpr (PARTIAL) {
        float* P = blockIdx.z ? (float*)Cout2 : (float*)Cout;
#pragma unroll
        for (int i = 0; i < 4; ++i)
#pragma unroll
            for (int j = 0; j < NJ; ++j)
#pragma unroll
                for (int r = 0; r < 4; ++r) {
                    int row = m0 + wr + i * 16 + quad * 4 + r;
                    int col = n0 + wc + j * 16 + l15;
                    P[(size_t)row * N + col] = acc[i][j][r];
                }
    } else {
#pragma unroll
        for (int i = 0; i < 4; ++i)
#pragma unroll
            for (int j = 0; j < NJ; ++j)
#pragma unroll
                for (int r = 0; r < 4; ++r) {
                    int row = m0 + wr + i * 16 + quad * 4 + r;
                    int col = n0 + wc + j * 16 + l15;
                    float v = acc[i][j][r];
                    if constexpr (BIAS)  v += bias[col];
                    if constexpr (GELU) {
                        // x*sigmoid(1.702x): exp2 + hw rcp (~6 VALU ops)
                        float e = exp2f(v * -2.4554674f);
                        v = v * __builtin_amdgcn_rcpf(1.0f + e);
                    }
                    if constexpr (RESID) v += resid[(size_t)row * N + col];
                    if constexpr (OUT_BF16) ((short*)Cout)[(size_t)row * N + col] = f2bf(v);
                    else                    ((float*)Cout)[(size_t)row * N + col] = v;
                }
    }
}

// ---------------------------------------------------------------------------
// Split-K reduce (2 slots): out = p0 + p1 + resid (+ bias).
// No __restrict__ on p0/out: they alias in the fc2 path.
// ---------------------------------------------------------------------------
template <bool BIAS>
__global__ __launch_bounds__(256) void reduce2(const float* p0,
                                               const float* p1,
                                               const float* resid,
                                               const float* bias,
                                               float* out, int N)
{
    size_t idx = ((size_t)blockIdx.x * 256 + threadIdx.x) * 4;
    float4 a = *(const float4*)(p0 + idx);
    float4 b = *(const float4*)(p1 + idx);
    float4 r = *(const float4*)(resid + idx);
    float4 v;
    v.x = a.x + b.x + r.x; v.y = a.y + b.y + r.y;
    v.z = a.z + b.z + r.z; v.w = a.w + b.w + r.w;
    if constexpr (BIAS) {
        const float4 bv = *(const float4*)(bias + (idx & (N - 1)));
        v.x += bv.x; v.y += bv.y; v.z += bv.z; v.w += bv.w;
    }
    *(float4*)(out + idx) = v;
}

// ---------------------------------------------------------------------------
// Split-K reduce + LayerNorm fusion (proj epilogue + ln2 in one pass).
// ---------------------------------------------------------------------------
__global__ __launch_bounds__(256) void reduce2_ln(const float* __restrict__ p0,
                                                  const float* __restrict__ p1,
                                                  const float* __restrict__ resid,
                                                  const float* __restrict__ lw,
                                                  const float* __restrict__ lb,
                                                  float* __restrict__ out_f32,
                                                  short* __restrict__ out_bf16)
{
    int row = blockIdx.x, tid = threadIdx.x;
    size_t idx = (size_t)row * 1024 + tid * 4;
    float4 a = *(const float4*)(p0 + idx);
    float4 b = *(const float4*)(p1 + idx);
    float4 r = *(const float4*)(resid + idx);
    float4 v;
    v.x = a.x + b.x + r.x; v.y = a.y + b.y + r.y;
    v.z = a.z + b.z + r.z; v.w = a.w + b.w + r.w;
    *(float4*)(out_f32 + idx) = v;
    float s = v.x + v.y + v.z + v.w;
    float q = v.x * v.x + v.y * v.y + v.z * v.z + v.w * v.w;
#pragma unroll
    for (int off = 32; off > 0; off >>= 1) {
        s += __shfl_down(s, off);
        q += __shfl_down(q, off);
    }
    __shared__ float ls[4], lq[4];
    if ((tid & 63) == 0) { ls[tid >> 6] = s; lq[tid >> 6] = q; }
    __syncthreads();
    float S  = ls[0] + ls[1] + ls[2] + ls[3];
    float Q  = lq[0] + lq[1] + lq[2] + lq[3];
    float mu  = S * (1.0f / 1024.0f);
    float var = Q * (1.0f / 1024.0f) - mu * mu;
    float inv = rsqrtf(var + 1e-5f);
    float4 wv = *(const float4*)(lw + tid * 4);
    float4 bv = *(const float4*)(lb + tid * 4);
    bf16x4 o;
    o[0] = f2bf((v.x - mu) * inv * wv.x + bv.x);
    o[1] = f2bf((v.y - mu) * inv * wv.y + bv.y);
    o[2] = f2bf((v.z - mu) * inv * wv.z + bv.z);
    o[3] = f2bf((v.w - mu) * inv * wv.w + bv.w);
    *(bf16x4*)(out_bf16 + idx) = o;
}

// ---------------------------------------------------------------------------
// Flash attention (causal).  R24: 4-wave blocks, 64-row Q tile, paired
// (qt=31-j then qt=j); KVBLK=128 staged as TWO 64-wide halves per barrier
// (layouts/swizzles identical to the verified 64-wide code).  Block iters
// 33 -> 17 uniform; fully-masked half (kt2>qt) skipped wave-uniformly.
// Grid (16,16,2)=512 blocks = 2/CU; LDS 64KB -> 2 blocks/CU preserved.
// ---------------------------------------------------------------------------
__global__ __launch_bounds__(256) void attn_kernel(const short* __restrict__ qkv,
                                                   const short* __restrict__ vt,
                                                   short* __restrict__ out)
{
    __shared__ short Ks[2][2][64 * 64];
    __shared__ short Vs[2][2][64 * 64];
    const float CS = 0.125f * 1.44269504088896f;  // 1/sqrt(64) * log2(e)
    int tid  = threadIdx.x, lane = tid & 63, wv = tid >> 6;   // wv in {0..3}
    int quad = lane >> 4, l15 = lane & 15;
    int b = blockIdx.z, h = blockIdx.y, j = blockIdx.x;

    const short* kq = qkv + (size_t)b * 2048 * 3072 + 1024 + h * 64;
    const short* vb = vt  + (size_t)(b * 16 + h) * 64 * 2048;
    int srow = lane >> 3;                 // 0..7 : row within 8-row chunk
    int scol = ((lane & 7) ^ srow) * 8;   // XOR-swizzled store granule
    int rg0  = (quad ^ (l15 & 7)) * 8;    // swizzled b128 read offset
    const bf16x4 vones = {(short)0x3F80, (short)0x3F80, (short)0x3F80, (short)0x3F80};

    for (int item = 0; item < 2; ++item) {
        int qt = item ? j : 31 - j;       // 64-row Q tile; long item first
        int q0 = qt * 64;
        int nkt = (qt >> 1) + 1;          // 128-wide k-tiles

        bf16x8 qf[2];
#pragma unroll
        for (int ks = 0; ks < 2; ++ks)
            qf[ks] = *(const bf16x8*)&qkv[(size_t)(b * 2048 + q0 + wv * 16 + l15) * 3072
                                           + h * 64 + ks * 32 + quad * 8];
        fx4 oacc[4] = {};
        fx4 lacc = {};

#pragma unroll
        for (int hh = 0; hh < 2; ++hh)
            for (int c = wv; c < 8; c += 4) {
                int row = c * 8 + srow;
                __builtin_amdgcn_global_load_lds(AS1(kq + (size_t)(hh * 64 + row) * 3072 + scol),
                                                 AS3(&Ks[0][hh][c * 512]), 16, 0, 0);
                __builtin_amdgcn_global_load_lds(AS1(vb + (size_t)row * 2048 + hh * 64 + scol),
                                                 AS3(&Vs[0][hh][c * 512]), 16, 0, 0);
            }
        __syncthreads();

        for (int kt = 0; kt < nkt; ++kt) {
            int cur = kt & 1;
            if (kt + 1 < nkt) {           // stage next 128-k tile into alt buffer
                int nb = cur ^ 1, tn = (kt + 1) * 128;
#pragma unroll
                for (int hh = 0; hh < 2; ++hh)
                    for (int c = wv; c < 8; c += 4) {
                        int row = c * 8 + srow;
                        __builtin_amdgcn_global_load_lds(AS1(kq + (size_t)(tn + hh * 64 + row) * 3072 + scol),
                                                         AS3(&Ks[nb][hh][c * 512]), 16, 0, 0);
                        __builtin_amdgcn_global_load_lds(AS1(vb + (size_t)row * 2048 + tn + hh * 64 + scol),
                                                         AS3(&Vs[nb][hh][c * 512]), 16, 0, 0);
                    }
            }

#pragma unroll
            for (int hh = 0; hh < 2; ++hh) {
                int kt2 = kt * 2 + hh;    // 64-wide k-tile index
                if (kt2 <= qt) {          // skip fully-masked half (wave-uniform)
                    fx4 s[4];
#pragma unroll
                    for (int nt = 0; nt < 4; ++nt) {
                        bf16x8 kf0 = *(const bf16x8*)&Ks[cur][hh][(nt * 16 + l15) * 64 + rg0];
                        bf16x8 kf1 = *(const bf16x8*)&Ks[cur][hh][(nt * 16 + l15) * 64 + (rg0 ^ 32)];
                        fx4 z = {0.f, 0.f, 0.f, 0.f};
                        z = __builtin_amdgcn_mfma_f32_16x16x32_bf16(kf0, qf[0], z, 0, 0, 0);
                        z = __builtin_amdgcn_mfma_f32_16x16x32_bf16(kf1, qf[1], z, 0, 0, 0);
                        s[nt] = z;
                    }
                    if (kt2 == qt) {      // diagonal tile: causal mask
                        int delta = wv * 16 + l15;           // q - tile base
#pragma unroll
                        for (int nt = 0; nt < 4; ++nt)
#pragma unroll
                            for (int r = 0; r < 4; ++r)
                                if (nt * 16 + quad * 4 + r > delta) s[nt][r] = -1e30f;
                    }

                    bf16x4 pf[4];
#pragma unroll
                    for (int nt = 0; nt < 4; ++nt) {
                        float p0 = exp2f(s[nt][0] * CS);
                        float p1 = exp2f(s[nt][1] * CS);
                        float p2 = exp2f(s[nt][2] * CS);
                        float p3 = exp2f(s[nt][3] * CS);
                        unsigned a0 = __builtin_bit_cast(unsigned, p0) + 0x8000u;
                        unsigned a1 = __builtin_bit_cast(unsigned, p1) + 0x8000u;
                        unsigned a2 = __builtin_bit_cast(unsigned, p2) + 0x8000u;
                        unsigned a3 = __builtin_bit_cast(unsigned, p3) + 0x8000u;
                        ix2 pk;
                        pk[0] = (int)__builtin_amdgcn_perm(a1, a0, 0x07060302u);
                        pk[1] = (int)__builtin_amdgcn_perm(a3, a2, 0x07060302u);
                        pf[nt] = __builtin_bit_cast(bf16x4, pk);
                    }
#pragma unroll
                    for (int nt = 0; nt < 4; ++nt)
                        lacc = __builtin_amdgcn_mfma_f32_16x16x16bf16_1k(pf[nt], vones, lacc, 0, 0, 0);
#pragma unroll
                    for (int dt = 0; dt < 4; ++dt) {
                        int vrow  = dt * 16 + l15;
                        int rbase = vrow * 64 + (quad & 1) * 4;
                        int rk    = vrow & 7;
#pragma unroll
                        for (int nt = 0; nt < 4; ++nt) {
                            int g = (nt * 2 + (quad >> 1)) ^ rk;
                            bf16x4 vf = *(const bf16x4*)&Vs[cur][hh][rbase + g * 8];
                            oacc[dt] = __builtin_amdgcn_mfma_f32_16x16x16bf16_1k(pf[nt], vf, oacc[dt], 0, 0, 0);
                        }
                    }
                }
            }
            __syncthreads();
        }

        float linv[4];
#pragma unroll
        for (int r = 0; r < 4; ++r) linv[r] = 1.0f / lacc[r];
#pragma unroll
        for (int dt = 0; dt < 4; ++dt)
#pragma unroll
            for (int r = 0; r < 4; ++r) {
                int row = q0 + wv * 16 + quad * 4 + r;
                int col = h * 64 + dt * 16 + l15;
                out[((size_t)b * 2048 + row) * 1024 + col] = f2bf(oacc[dt][r] * linv[r]);
            }
    }
}

// ---------------------------------------------------------------------------
extern "C" void kernel_launch(void* const* d_in, const int* in_sizes, int n_in,
                              void* d_out, int out_size, void* d_ws, size_t ws_size,
                              hipStream_t stream)
{
    const float* x      = (const float*)d_in[0];
    const float* w_qkv  = (const float*)d_in[1];
    const float* w_proj = (const float*)d_in[2];
    const float* ln1_w  = (const float*)d_in[3];
    const float* ln1_b  = (const float*)d_in[4];
    const float* ln2_w  = (const float*)d_in[5];
    const float* ln2_b  = (const float*)d_in[6];
    const float* fc1_w  = (const float*)d_in[7];
    const float* fc1_b  = (const float*)d_in[8];
    const float* fc2_w  = (const float*)d_in[9];
    const float* fc2_b  = (const float*)d_in[10];
    float* out = (float*)d_out;
    char*  ws  = (char*)d_ws;

    size_t off = 0;
    auto alloc = [&](size_t bytes) { void* p = ws + off; off += (bytes + 255) & ~(size_t)255; return p; };
    short* tw_qkv  = (short*)alloc((size_t)3072 * 1024 * 2);
    short* tw_proj = (short*)alloc((size_t)1024 * 1024 * 2);
    short* tfc1    = (short*)alloc((size_t)4096 * 1024 * 2);
    short* tfc2    = (short*)alloc((size_t)1024 * 4096 * 2);
    short* xn      = (short*)alloc((size_t)4096 * 1024 * 2);
    short* qkvb    = (short*)alloc((size_t)4096 * 3072 * 2);
    short* vtb     = (short*)alloc((size_t)32 * 64 * 2048 * 2);
    short* attnb   = (short*)alloc((size_t)4096 * 1024 * 2);
    float* x1      = (float*)alloc((size_t)4096 * 1024 * 4);
    float* pk      = (float*)alloc((size_t)4096 * 1024 * 4);  // split-K slot 1
    short* h1      = qkvb;  // alias: spans qkvb+vtb (33.55MB); both dead after attn

    transpose_f32_bf16<<<dim3(3072 / 64, 1024 / 64), 256, 0, stream>>>(w_qkv, tw_qkv, 1024, 3072);
    transpose_f32_bf16<<<dim3(1024 / 64, 1024 / 64), 256, 0, stream>>>(w_proj, tw_proj, 1024, 1024);
    transpose_f32_bf16<<<dim3(4096 / 64, 1024 / 64), 256, 0, stream>>>(fc1_w, tfc1, 1024, 4096);
    transpose_f32_bf16<<<dim3(1024 / 64, 4096 / 64), 256, 0, stream>>>(fc2_w, tfc2, 4096, 1024);

    ln_kernel<<<4096, 256, 0, stream>>>(x, ln1_w, ln1_b, xn);
    gemm_bt<256, 128, 32, 0, 1, false, false, false, true, false><<<dim3(24, 16, 1), 512, 0, stream>>>(
        xn, tw_qkv, qkvb, nullptr, nullptr, nullptr, 4096, 3072, 1024);
    vt_extract<<<dim3(2048 / 32, 64 / 32, 32), dim3(32, 8), 0, stream>>>(qkvb, vtb);
    attn_kernel<<<dim3(16, 16, 2), 256, 0, stream>>>(qkvb, vtb, attnb);
    gemm_bt<128, 64, 32, 0, 1, false, false, false, false, true><<<dim3(16, 32, 2), 256, 0, stream>>>(
        attnb, tw_proj, x1, pk, nullptr, nullptr, 4096, 1024, 1024);
    reduce2_ln<<<4096, 256, 0, stream>>>(x1, pk, x, ln2_w, ln2_b, x1, xn);
    gemm_bt<256, 128, 32, 0, 1, true, true, false, true, false><<<dim3(32, 16, 1), 512, 0, stream>>>(
        xn, tfc1, h1, nullptr, fc1_b, nullptr, 4096, 4096, 1024);
    gemm_bt<128, 128, 64, 1, 1, false, false, false, false, true><<<dim3(8, 32, 2), 256, 0, stream>>>(
        h1, tfc2, out, pk, nullptr, nullptr, 4096, 1024, 4096);
    reduce2<true><<<4096, 256, 0, stream>>>(out, pk, x1, fc2_b, out, 1024);
}

// Round 17
// 330.341 us; speedup vs baseline: 1.0602x; 1.0602x over previous
//
#include <hip/hip_runtime.h>

// ---------------------------------------------------------------------------
// Transformer block for MI355X (gfx950).
// R25: fused dual-Q attention.  R24 post-mortem: KVBLK=128 HURT (56.0->58.9,
// VALUBusy 44.6->49) -- attn is VALU-regime (softmax exp2), not
// barrier-regime; the per-CU-iter lever doesn't apply there (rule #23:
// regime-check before applying a lever).  Revert to R23's verified 64-wide
// body, and instead REDUCE TOTAL WORK: item_lo's K/V range [0,jj] is a
// subset of item_hi's [0,31-jj], so fuse both Q-tiles into ONE k-loop --
// stage K/V once, compute hi every iter, lo only while kt <= jj.  Block
// iters 33 -> 32-jj (total 528->392 per (h,b), -26% barriers+staging).
// Length imbalance (17..32) anti-correlated across batch: jj = b?15-j:j,
// so each CU's two blocks (id, id+256: same j, different b) sum to 49
// iters uniformly; if co-location fails, worst CU = 64 < current 66.
// VGPR ~90 (2nd acc set), LDS 32KB, 2 blocks/CU.  GEMMs = R23 config
// (qkv/fc1 BM=256 BK=32; proj BN=64; fc2 BK=64+SWZ; PIPE=1).
// ---------------------------------------------------------------------------

typedef short  bf16x8 __attribute__((ext_vector_type(8)));
typedef short  bf16x4 __attribute__((ext_vector_type(4)));
typedef float  fx4    __attribute__((ext_vector_type(4)));
typedef int    ix2    __attribute__((ext_vector_type(2)));

#define DEV static __device__ __forceinline__

DEV short f2bf(float f) {                 // round-to-nearest-even fp32 -> bf16
    unsigned u = __builtin_bit_cast(unsigned, f);
    u += 0x7fffu + ((u >> 16) & 1u);
    return (short)(u >> 16);
}

// address-space casts for global_load_lds
#define AS1(p) ((__attribute__((address_space(1))) void*)(p))
#define AS3(p) ((__attribute__((address_space(3))) void*)(p))

// ---------------------------------------------------------------------------
// LayerNorm: fp32 [4096][1024] -> bf16 [4096][1024].  One block (256t) / row.
// ---------------------------------------------------------------------------
__global__ __launch_bounds__(256) void ln_kernel(const float* __restrict__ x,
                                                 const float* __restrict__ w,
                                                 const float* __restrict__ b,
                                                 short* __restrict__ out)
{
    int row = blockIdx.x;
    int tid = threadIdx.x;
    const float4 v = *(const float4*)(x + (size_t)row * 1024 + tid * 4);
    float s = v.x + v.y + v.z + v.w;
    float q = v.x * v.x + v.y * v.y + v.z * v.z + v.w * v.w;
#pragma unroll
    for (int off = 32; off > 0; off >>= 1) {
        s += __shfl_down(s, off);
        q += __shfl_down(q, off);
    }
    __shared__ float ls[4], lq[4];
    if ((tid & 63) == 0) { ls[tid >> 6] = s; lq[tid >> 6] = q; }
    __syncthreads();
    float S  = ls[0] + ls[1] + ls[2] + ls[3];
    float Q  = lq[0] + lq[1] + lq[2] + lq[3];
    float mu  = S * (1.0f / 1024.0f);
    float var = Q * (1.0f / 1024.0f) - mu * mu;
    float inv = rsqrtf(var + 1e-5f);
    float4 wv = *(const float4*)(w + tid * 4);
    float4 bv = *(const float4*)(b + tid * 4);
    bf16x4 o;
    o[0] = f2bf((v.x - mu) * inv * wv.x + bv.x);
    o[1] = f2bf((v.y - mu) * inv * wv.y + bv.y);
    o[2] = f2bf((v.z - mu) * inv * wv.z + bv.z);
    o[3] = f2bf((v.w - mu) * inv * wv.w + bv.w);
    *(bf16x4*)(out + (size_t)row * 1024 + tid * 4) = o;
}

// ---------------------------------------------------------------------------
// Weight transpose+cast: fp32 [R][C] -> bf16 [C][R].  64x64 tiles, 256 thr.
// ---------------------------------------------------------------------------
__global__ __launch_bounds__(256) void transpose_f32_bf16(const float* __restrict__ in,
                                                          short* __restrict__ out,
                                                          int R, int C)
{
    __shared__ float tile[64][65];
    int c0 = blockIdx.x * 64, r0 = blockIdx.y * 64;
    int t  = threadIdx.x;
    int tx = t & 15, ty = t >> 4;            // load: 16 col-segs x 16 rows
#pragma unroll
    for (int i = 0; i < 4; ++i) {
        int row = i * 16 + ty;
        float4 v = *(const float4*)(in + (size_t)(r0 + row) * C + c0 + tx * 4);
        tile[row][tx * 4 + 0] = v.x;
        tile[row][tx * 4 + 1] = v.y;
        tile[row][tx * 4 + 2] = v.z;
        tile[row][tx * 4 + 3] = v.w;
    }
    __syncthreads();
    int seg = t & 7;                         // out-row segment (8 in-rows)
#pragma unroll
    for (int p = 0; p < 2; ++p) {
        int orow = p * 32 + (t >> 3);        // out row = in col
        bf16x8 o;
#pragma unroll
        for (int u = 0; u < 8; ++u)
            o[u] = f2bf(tile[seg * 8 + u][orow]);
        *(bf16x8*)(out + (size_t)(c0 + orow) * R + r0 + seg * 8) = o;
    }
}

// ---------------------------------------------------------------------------
// Extract V^T per (b,h): qkv bf16 [4096][3072] cols[2048+h*64 .. +64)
//   -> vt [b][h][64][2048] (d-major, t contiguous) for PV's B-operand.
// ---------------------------------------------------------------------------
__global__ void vt_extract(const short* __restrict__ qkv, short* __restrict__ vt)
{
    __shared__ short tile[32][33];
    int t0 = blockIdx.x * 32, d0 = blockIdx.y * 32;
    int bh = blockIdx.z;                       // b*16 + h
    int tx = threadIdx.x, ty = threadIdx.y;
    size_t inbase  = (size_t)(bh >> 4) * 2048 * 3072 + 2048 + (bh & 15) * 64;
    size_t outbase = (size_t)bh * 64 * 2048;
#pragma unroll
    for (int dy = 0; dy < 32; dy += 8)
        tile[ty + dy][tx] = qkv[inbase + (size_t)(t0 + ty + dy) * 3072 + d0 + tx];
    __syncthreads();
#pragma unroll
    for (int dy = 0; dy < 32; dy += 8)
        vt[outbase + (size_t)(d0 + ty + dy) * 2048 + t0 + tx] = tile[tx][ty + dy];
}

// ---------------------------------------------------------------------------
// GEMM  C[M][N] = epi( A[M][K](bf16) * Bt[N][K](bf16)^T )
// BMxBN tile, NW=BM/32 waves (2*BM threads); each wave owns a 64x(BN/2)
// sub-tile: wr=(wv>>1)*64, wc=(wv&1)*(BN/2).  BK in {32,64},
// global_load_lds(16B), double-buffered LDS.  PIPE=1: counted-vmcnt
// 2-barrier loop; PIPE=0: classic full-drain loop.
// Swizzle: GR=BK/8 granules/row; LDS[row][g] = global[g ^ ((row>>1)&(GR-1))];
// k-half h read at granule (h*4+quad)^fr -> 2-way max bank spread.
// SWZ=1: XCD-aware block swizzle (bijective when gridDim.x*gridDim.y%8==0).
// ---------------------------------------------------------------------------
template <int BM, int BN, int BK, int SWZ, int PIPE, bool BIAS, bool GELU, bool RESID, bool OUT_BF16, bool PARTIAL>
__global__ __launch_bounds__(2 * BM) void gemm_bt(const short* __restrict__ A,
                                                  const short* __restrict__ Bt,
                                                  void* __restrict__ Cout,
                                                  void* __restrict__ Cout2,
                                                  const float* __restrict__ bias,
                                                  const float* __restrict__ resid,
                                                  int M, int N, int K)
{
    constexpr int NJ  = BN / 32;                   // 16-col tiles per wave
    constexpr int NW  = BM / 32;                   // waves per block
    constexpr int GR  = BK / 8;                    // granule slots per row
    constexpr int RPC = 512 / BK;                  // rows per 1KB chunk
    constexpr int NA  = (BM * BK) / 512;           // A chunks per buffer
    constexpr int NB  = (BN * BK) / 512;           // B chunks per buffer
    constexpr int LPS = (NA + NB) / NW;            // gload_lds per wave/stage
    __shared__ short As[2][BM * BK];
    __shared__ short Bs[2][BN * BK];
    int tid  = threadIdx.x;
    int lane = tid & 63, wv = tid >> 6;
    int quad = lane >> 4, l15 = lane & 15;
    int bx = blockIdx.x, by = blockIdx.y;
    if constexpr (SWZ) {
        int nx   = gridDim.x;
        int nper = nx * gridDim.y;                 // blocks per z-slice
        int flat = bx + nx * by;
        int cpx  = nper >> 3;                      // chunk per XCD
        int swz  = (flat & 7) * cpx + (flat >> 3); // bijective: nper % 8 == 0
        bx = swz % nx;
        by = swz / nx;
    }
    int m0 = by * BM, n0 = bx * BN;
    int SK   = gridDim.z;
    int kbeg = blockIdx.z * (K / SK);
    int NK   = (K / SK) / BK;
    int wr = (wv >> 1) * 64, wc = (wv & 1) * (BN / 2);
    fx4 acc[4][NJ] = {};
    int srow = lane / GR;                          // row within chunk
    int gl   = lane % GR;                          // granule slot
    int fr   = (l15 >> 1) & (GR - 1);              // fragment-read row XOR
    const short* Ab = A  + (size_t)m0 * K;
    const short* Bb = Bt + (size_t)n0 * K;

    auto stage = [&](int buf, int k0) {
#pragma unroll
        for (int c = wv; c < NA; c += NW) {
            int row  = c * RPC + srow;
            int scol = (gl ^ ((row >> 1) & (GR - 1))) * 8;
            __builtin_amdgcn_global_load_lds(AS1(Ab + (size_t)row * K + k0 + scol),
                                             AS3(&As[buf][c * 512]), 16, 0, 0);
        }
#pragma unroll
        for (int c = wv; c < NB; c += NW) {
            int row  = c * RPC + srow;
            int scol = (gl ^ ((row >> 1) & (GR - 1))) * 8;
            __builtin_amdgcn_global_load_lds(AS1(Bb + (size_t)row * K + k0 + scol),
                                             AS3(&Bs[buf][c * 512]), 16, 0, 0);
        }
    };

    auto compute_tile = [&](int cur) {
#pragma unroll
        for (int h = 0; h < BK / 32; ++h) {
            int rg = ((h * 4 + quad) ^ fr) * 8;
            bf16x8 af[4], bfr[NJ];
#pragma unroll
            for (int i = 0; i < 4; ++i)
                af[i] = *(const bf16x8*)&As[cur][(wr + i * 16 + l15) * BK + rg];
#pragma unroll
            for (int j = 0; j < NJ; ++j)
                bfr[j] = *(const bf16x8*)&Bs[cur][(wc + j * 16 + l15) * BK + rg];
#pragma unroll
            for (int i = 0; i < 4; ++i)
#pragma unroll
                for (int j = 0; j < NJ; ++j)
                    acc[i][j] = __builtin_amdgcn_mfma_f32_16x16x32_bf16(af[i], bfr[j], acc[i][j], 0, 0, 0);
        }
    };

    stage(0, kbeg);
    if constexpr (PIPE) {
        // Counted-vmcnt 2-barrier loop: prev tile's loads drained per-wave,
        // this tile's loads stay in flight across both barriers.
        for (int kt = 0; kt < NK; ++kt) {
            int cur = kt & 1;
            if (kt + 1 < NK) {
                stage(cur ^ 1, kbeg + (kt + 1) * BK);
                if constexpr      (LPS == 3) asm volatile("s_waitcnt vmcnt(3)" ::: "memory");
                else if constexpr (LPS == 4) asm volatile("s_waitcnt vmcnt(4)" ::: "memory");
                else if constexpr (LPS == 8) asm volatile("s_waitcnt vmcnt(8)" ::: "memory");
                else                         asm volatile("s_waitcnt vmcnt(0)" ::: "memory");
            } else {
                asm volatile("s_waitcnt vmcnt(0)" ::: "memory");
            }
            asm volatile("s_barrier" ::: "memory");   // B1: all waves' tile-kt loads done
            compute_tile(cur);
            asm volatile("s_barrier" ::: "memory");   // B2: all waves done reading buf[cur]
        }
    } else {
        __syncthreads();
        for (int kt = 0; kt < NK; ++kt) {
            int cur = kt & 1;
            if (kt + 1 < NK) stage(cur ^ 1, kbeg + (kt + 1) * BK);
            compute_tile(cur);
            __syncthreads();
        }
    }

    if constexpr (PARTIAL) {
        float* P = blockIdx.z ? (float*)Cout2 : (float*)Cout;
#pragma unroll
        for (int i = 0; i < 4; ++i)
#pragma unroll
            for (int j = 0; j < NJ; ++j)
#pragma unroll
                for (int r = 0; r < 4; ++r) {
                    int row = m0 + wr + i * 16 + quad * 4 + r;
                    int col = n0 + wc + j * 16 + l15;
                    P[(size_t)row * N + col] = acc[i][j][r];
                }
    } else {
#pragma unroll
        for (int i = 0; i < 4; ++i)
#pragma unroll
            for (int j = 0; j < NJ; ++j)
#pragma unroll
                for (int r = 0; r < 4; ++r) {
                    int row = m0 + wr + i * 16 + quad * 4 + r;
                    int col = n0 + wc + j * 16 + l15;
                    float v = acc[i][j][r];
                    if constexpr (BIAS)  v += bias[col];
                    if constexpr (GELU) {
                        // x*sigmoid(1.702x): exp2 + hw rcp (~6 VALU ops)
                        float e = exp2f(v * -2.4554674f);
                        v = v * __builtin_amdgcn_rcpf(1.0f + e);
                    }
                    if constexpr (RESID) v += resid[(size_t)row * N + col];
                    if constexpr (OUT_BF16) ((short*)Cout)[(size_t)row * N + col] = f2bf(v);
                    else                    ((float*)Cout)[(size_t)row * N + col] = v;
                }
    }
}

// ---------------------------------------------------------------------------
// Split-K reduce (2 slots): out = p0 + p1 + resid (+ bias).
// No __restrict__ on p0/out: they alias in the fc2 path.
// ---------------------------------------------------------------------------
template <bool BIAS>
__global__ __launch_bounds__(256) void reduce2(const float* p0,
                                               const float* p1,
                                               const float* resid,
                                               const float* bias,
                                               float* out, int N)
{
    size_t idx = ((size_t)blockIdx.x * 256 + threadIdx.x) * 4;
    float4 a = *(const float4*)(p0 + idx);
    float4 b = *(const float4*)(p1 + idx);
    float4 r = *(const float4*)(resid + idx);
    float4 v;
    v.x = a.x + b.x + r.x; v.y = a.y + b.y + r.y;
    v.z = a.z + b.z + r.z; v.w = a.w + b.w + r.w;
    if constexpr (BIAS) {
        const float4 bv = *(const float4*)(bias + (idx & (N - 1)));
        v.x += bv.x; v.y += bv.y; v.z += bv.z; v.w += bv.w;
    }
    *(float4*)(out + idx) = v;
}

// ---------------------------------------------------------------------------
// Split-K reduce + LayerNorm fusion (proj epilogue + ln2 in one pass).
// ---------------------------------------------------------------------------
__global__ __launch_bounds__(256) void reduce2_ln(const float* __restrict__ p0,
                                                  const float* __restrict__ p1,
                                                  const float* __restrict__ resid,
                                                  const float* __restrict__ lw,
                                                  const float* __restrict__ lb,
                                                  float* __restrict__ out_f32,
                                                  short* __restrict__ out_bf16)
{
    int row = blockIdx.x, tid = threadIdx.x;
    size_t idx = (size_t)row * 1024 + tid * 4;
    float4 a = *(const float4*)(p0 + idx);
    float4 b = *(const float4*)(p1 + idx);
    float4 r = *(const float4*)(resid + idx);
    float4 v;
    v.x = a.x + b.x + r.x; v.y = a.y + b.y + r.y;
    v.z = a.z + b.z + r.z; v.w = a.w + b.w + r.w;
    *(float4*)(out_f32 + idx) = v;
    float s = v.x + v.y + v.z + v.w;
    float q = v.x * v.x + v.y * v.y + v.z * v.z + v.w * v.w;
#pragma unroll
    for (int off = 32; off > 0; off >>= 1) {
        s += __shfl_down(s, off);
        q += __shfl_down(q, off);
    }
    __shared__ float ls[4], lq[4];
    if ((tid & 63) == 0) { ls[tid >> 6] = s; lq[tid >> 6] = q; }
    __syncthreads();
    float S  = ls[0] + ls[1] + ls[2] + ls[3];
    float Q  = lq[0] + lq[1] + lq[2] + lq[3];
    float mu  = S * (1.0f / 1024.0f);
    float var = Q * (1.0f / 1024.0f) - mu * mu;
    float inv = rsqrtf(var + 1e-5f);
    float4 wv = *(const float4*)(lw + tid * 4);
    float4 bv = *(const float4*)(lb + tid * 4);
    bf16x4 o;
    o[0] = f2bf((v.x - mu) * inv * wv.x + bv.x);
    o[1] = f2bf((v.y - mu) * inv * wv.y + bv.y);
    o[2] = f2bf((v.z - mu) * inv * wv.z + bv.z);
    o[3] = f2bf((v.w - mu) * inv * wv.w + bv.w);
    *(bf16x4*)(out_bf16 + idx) = o;
}

// ---------------------------------------------------------------------------
// Flash attention (causal).  R25: fused dual-Q.  Block handles qt_hi=31-jj
// (full k-range) and qt_lo=jj (prefix k-range) in ONE k-loop over nkt=32-jj
// 64-wide tiles; K/V staged once.  jj = b?15-j:j anti-correlates block
// lengths across the two batch elements so each CU's pair sums to 49 iters.
// Per-item body identical to R23's verified 64-wide code.  LDS 32KB.
// ---------------------------------------------------------------------------
__global__ __launch_bounds__(256) void attn_kernel(const short* __restrict__ qkv,
                                                   const short* __restrict__ vt,
                                                   short* __restrict__ out)
{
    __shared__ short Ks[2][64 * 64];
    __shared__ short Vs[2][64 * 64];
    const float CS = 0.125f * 1.44269504088896f;  // 1/sqrt(64) * log2(e)
    int tid  = threadIdx.x, lane = tid & 63, wv = tid >> 6;   // wv in {0..3}
    int quad = lane >> 4, l15 = lane & 15;
    int b = blockIdx.z, h = blockIdx.y, j = blockIdx.x;
    int jj = b ? (15 - j) : j;            // CU-pair balance: lengths sum to 49
    int qt_hi = 31 - jj, qt_lo = jj;
    int q0_hi = qt_hi * 64, q0_lo = qt_lo * 64;
    int nkt = qt_hi + 1;                  // 64-wide k-tiles = 32 - jj

    const short* kq = qkv + (size_t)b * 2048 * 3072 + 1024 + h * 64;
    const short* vb = vt  + (size_t)(b * 16 + h) * 64 * 2048;
    int srow = lane >> 3;                 // 0..7 : row within 8-row chunk
    int scol = ((lane & 7) ^ srow) * 8;   // XOR-swizzled store granule
    int rg0  = (quad ^ (l15 & 7)) * 8;    // swizzled b128 read offset
    const bf16x4 vones = {(short)0x3F80, (short)0x3F80, (short)0x3F80, (short)0x3F80};

    bf16x8 qfh[2], qfl[2];
#pragma unroll
    for (int ks = 0; ks < 2; ++ks) {
        qfh[ks] = *(const bf16x8*)&qkv[(size_t)(b * 2048 + q0_hi + wv * 16 + l15) * 3072
                                        + h * 64 + ks * 32 + quad * 8];
        qfl[ks] = *(const bf16x8*)&qkv[(size_t)(b * 2048 + q0_lo + wv * 16 + l15) * 3072
                                        + h * 64 + ks * 32 + quad * 8];
    }
    fx4 oh[4] = {}, ol[4] = {};
    fx4 lh = {}, ll = {};

#pragma unroll
    for (int c = wv; c < 8; c += 4) {
        int row = c * 8 + srow;
        __builtin_amdgcn_global_load_lds(AS1(kq + (size_t)row * 3072 + scol),
                                         AS3(&Ks[0][c * 512]), 16, 0, 0);
        __builtin_amdgcn_global_load_lds(AS1(vb + (size_t)row * 2048 + scol),
                                         AS3(&Vs[0][c * 512]), 16, 0, 0);
    }
    __syncthreads();

    // one Q-item's full per-tile pipeline (identical math to R23)
    auto body = [&](const bf16x8 (&qf)[2], fx4 (&oacc)[4], fx4& lacc,
                    int qt, int kt, int cur) {
        fx4 s[4];
#pragma unroll
        for (int nt = 0; nt < 4; ++nt) {
            bf16x8 kf0 = *(const bf16x8*)&Ks[cur][(nt * 16 + l15) * 64 + rg0];
            bf16x8 kf1 = *(const bf16x8*)&Ks[cur][(nt * 16 + l15) * 64 + (rg0 ^ 32)];
            fx4 z = {0.f, 0.f, 0.f, 0.f};
            z = __builtin_amdgcn_mfma_f32_16x16x32_bf16(kf0, qf[0], z, 0, 0, 0);
            z = __builtin_amdgcn_mfma_f32_16x16x32_bf16(kf1, qf[1], z, 0, 0, 0);
            s[nt] = z;
        }
        if (kt == qt) {                   // diagonal tile: causal mask
            int delta = wv * 16 + l15;    // q - tile base
#pragma unroll
            for (int nt = 0; nt < 4; ++nt)
#pragma unroll
                for (int r = 0; r < 4; ++r)
                    if (nt * 16 + quad * 4 + r > delta) s[nt][r] = -1e30f;
        }

        bf16x4 pf[4];
#pragma unroll
        for (int nt = 0; nt < 4; ++nt) {
            float p0 = exp2f(s[nt][0] * CS);
            float p1 = exp2f(s[nt][1] * CS);
            float p2 = exp2f(s[nt][2] * CS);
            float p3 = exp2f(s[nt][3] * CS);
            unsigned a0 = __builtin_bit_cast(unsigned, p0) + 0x8000u;
            unsigned a1 = __builtin_bit_cast(unsigned, p1) + 0x8000u;
            unsigned a2 = __builtin_bit_cast(unsigned, p2) + 0x8000u;
            unsigned a3 = __builtin_bit_cast(unsigned, p3) + 0x8000u;
            ix2 pk;
            pk[0] = (int)__builtin_amdgcn_perm(a1, a0, 0x07060302u);
            pk[1] = (int)__builtin_amdgcn_perm(a3, a2, 0x07060302u);
            pf[nt] = __builtin_bit_cast(bf16x4, pk);
        }
#pragma unroll
        for (int nt = 0; nt < 4; ++nt)
            lacc = __builtin_amdgcn_mfma_f32_16x16x16bf16_1k(pf[nt], vones, lacc, 0, 0, 0);
#pragma unroll
        for (int dt = 0; dt < 4; ++dt) {
            int vrow  = dt * 16 + l15;
            int rbase = vrow * 64 + (quad & 1) * 4;
            int rk    = vrow & 7;
#pragma unroll
            for (int nt = 0; nt < 4; ++nt) {
                int g = (nt * 2 + (quad >> 1)) ^ rk;
                bf16x4 vf = *(const bf16x4*)&Vs[cur][rbase + g * 8];
                oacc[dt] = __builtin_amdgcn_mfma_f32_16x16x16bf16_1k(pf[nt], vf, oacc[dt], 0, 0, 0);
            }
        }
    };

    for (int kt = 0; kt < nkt; ++kt) {
        int cur = kt & 1;
        if (kt + 1 < nkt) {               // stage next tile into alt buffer
            int nb = cur ^ 1, tn = (kt + 1) * 64;
#pragma unroll
            for (int c = wv; c < 8; c += 4) {
                int row = c * 8 + srow;
                __builtin_amdgcn_global_load_lds(AS1(kq + (size_t)(tn + row) * 3072 + scol),
                                                 AS3(&Ks[nb][c * 512]), 16, 0, 0);
                __builtin_amdgcn_global_load_lds(AS1(vb + (size_t)row * 2048 + tn + scol),
                                                 AS3(&Vs[nb][c * 512]), 16, 0, 0);
            }
        }

        body(qfh, oh, lh, qt_hi, kt, cur);
        if (kt <= qt_lo) body(qfl, ol, ll, qt_lo, kt, cur);
        __syncthreads();
    }

    float lih[4], lil[4];
#pragma unroll
    for (int r = 0; r < 4; ++r) { lih[r] = 1.0f / lh[r]; lil[r] = 1.0f / ll[r]; }
#pragma unroll
    for (int dt = 0; dt < 4; ++dt)
#pragma unroll
        for (int r = 0; r < 4; ++r) {
            int rowh = q0_hi + wv * 16 + quad * 4 + r;
            int rowl = q0_lo + wv * 16 + quad * 4 + r;
            int col  = h * 64 + dt * 16 + l15;
            out[((size_t)b * 2048 + rowh) * 1024 + col] = f2bf(oh[dt][r] * lih[r]);
            out[((size_t)b * 2048 + rowl) * 1024 + col] = f2bf(ol[dt][r] * lil[r]);
        }
}

// ---------------------------------------------------------------------------
extern "C" void kernel_launch(void* const* d_in, const int* in_sizes, int n_in,
                              void* d_out, int out_size, void* d_ws, size_t ws_size,
                              hipStream_t stream)
{
    const float* x      = (const float*)d_in[0];
    const float* w_qkv  = (const float*)d_in[1];
    const float* w_proj = (const float*)d_in[2];
    const float* ln1_w  = (const float*)d_in[3];
    const float* ln1_b  = (const float*)d_in[4];
    const float* ln2_w  = (const float*)d_in[5];
    const float* ln2_b  = (const float*)d_in[6];
    const float* fc1_w  = (const float*)d_in[7];
    const float* fc1_b  = (const float*)d_in[8];
    const float* fc2_w  = (const float*)d_in[9];
    const float* fc2_b  = (const float*)d_in[10];
    float* out = (float*)d_out;
    char*  ws  = (char*)d_ws;

    size_t off = 0;
    auto alloc = [&](size_t bytes) { void* p = ws + off; off += (bytes + 255) & ~(size_t)255; return p; };
    short* tw_qkv  = (short*)alloc((size_t)3072 * 1024 * 2);
    short* tw_proj = (short*)alloc((size_t)1024 * 1024 * 2);
    short* tfc1    = (short*)alloc((size_t)4096 * 1024 * 2);
    short* tfc2    = (short*)alloc((size_t)1024 * 4096 * 2);
    short* xn      = (short*)alloc((size_t)4096 * 1024 * 2);
    short* qkvb    = (short*)alloc((size_t)4096 * 3072 * 2);
    short* vtb     = (short*)alloc((size_t)32 * 64 * 2048 * 2);
    short* attnb   = (short*)alloc((size_t)4096 * 1024 * 2);
    float* x1      = (float*)alloc((size_t)4096 * 1024 * 4);
    float* pk      = (float*)alloc((size_t)4096 * 1024 * 4);  // split-K slot 1
    short* h1      = qkvb;  // alias: spans qkvb+vtb (33.55MB); both dead after attn

    transpose_f32_bf16<<<dim3(3072 / 64, 1024 / 64), 256, 0, stream>>>(w_qkv, tw_qkv, 1024, 3072);
    transpose_f32_bf16<<<dim3(1024 / 64, 1024 / 64), 256, 0, stream>>>(w_proj, tw_proj, 1024, 1024);
    transpose_f32_bf16<<<dim3(4096 / 64, 1024 / 64), 256, 0, stream>>>(fc1_w, tfc1, 1024, 4096);
    transpose_f32_bf16<<<dim3(1024 / 64, 4096 / 64), 256, 0, stream>>>(fc2_w, tfc2, 4096, 1024);

    ln_kernel<<<4096, 256, 0, stream>>>(x, ln1_w, ln1_b, xn);
    gemm_bt<256, 128, 32, 0, 1, false, false, false, true, false><<<dim3(24, 16, 1), 512, 0, stream>>>(
        xn, tw_qkv, qkvb, nullptr, nullptr, nullptr, 4096, 3072, 1024);
    vt_extract<<<dim3(2048 / 32, 64 / 32, 32), dim3(32, 8), 0, stream>>>(qkvb, vtb);
    attn_kernel<<<dim3(16, 16, 2), 256, 0, stream>>>(qkvb, vtb, attnb);
    gemm_bt<128, 64, 32, 0, 1, false, false, false, false, true><<<dim3(16, 32, 2), 256, 0, stream>>>(
        attnb, tw_proj, x1, pk, nullptr, nullptr, 4096, 1024, 1024);
    reduce2_ln<<<4096, 256, 0, stream>>>(x1, pk, x, ln2_w, ln2_b, x1, xn);
    gemm_bt<256, 128, 32, 0, 1, true, true, false, true, false><<<dim3(32, 16, 1), 512, 0, stream>>>(
        xn, tfc1, h1, nullptr, fc1_b, nullptr, 4096, 4096, 1024);
    gemm_bt<128, 128, 64, 1, 1, false, false, false, false, true><<<dim3(8, 32, 2), 256, 0, stream>>>(
        h1, tfc2, out, pk, nullptr, nullptr, 4096, 1024, 4096);
    reduce2<true><<<4096, 256, 0, stream>>>(out, pk, x1, fc2_b, out, 1024);
}